// Round 17
// baseline (109.280 us; speedup 1.0000x reference)
//
#include <hip/hip_runtime.h>
#include <hip/hip_bf16.h>
#include <cstdint>

typedef __attribute__((ext_vector_type(8))) __bf16 bf16x8;
typedef __attribute__((ext_vector_type(4))) float f32x4;
typedef __attribute__((ext_vector_type(16))) float f32x16;

#define DM 1024
#define NH 16
#define DH 64
#define S_LEN 2048
#define BATCH 2

__device__ __forceinline__ ushort f2bf(float f) {
  union { float f; uint32_t u; } v; v.f = f;
  uint32_t u = v.u;
  uint32_t r = (u + 0x7fffu + ((u >> 16) & 1u)) >> 16;
  return (ushort)r;
}
__device__ __forceinline__ float bf2f(ushort h) {
  union { uint32_t u; float f; } v; v.u = ((uint32_t)h) << 16;
  return v.f;
}
__device__ __forceinline__ float bf2f_lo(uint32_t u) {
  union { uint32_t u; float f; } v; v.u = u << 16;
  return v.f;
}
__device__ __forceinline__ float bf2f_hi(uint32_t u) {
  union { uint32_t u; float f; } v; v.u = u & 0xffff0000u;
  return v.f;
}

__device__ __forceinline__ void gload16(const void* g, void* l) {
  __builtin_amdgcn_global_load_lds(
      (const __attribute__((address_space(1))) unsigned*)g,
      (__attribute__((address_space(3))) unsigned*)l, 16, 0, 0);
}

__device__ __forceinline__ float tsum16(const f32x16& v) {
  float a = (v[0] + v[1]) + (v[2] + v[3]);
  float b = (v[4] + v[5]) + (v[6] + v[7]);
  float c = (v[8] + v[9]) + (v[10] + v[11]);
  float d = (v[12] + v[13]) + (v[14] + v[15]);
  return (a + b) + (c + d);
}

// ---------------- prep: all f32->bf16 casts + rope table in one kernel ----------------
__global__ void prep(const float* __restrict__ x, const float* __restrict__ wqkv,
                     const float* __restrict__ wout,
                     ushort* __restrict__ xb, ushort* __restrict__ wqkvb,
                     ushort* __restrict__ woutb, float2* __restrict__ tab) {
  const int NX = 1048576, NW = 786432, NO = 262144, NT = 65536;
  for (int i = blockIdx.x * blockDim.x + threadIdx.x; i < NX + NW + NO + NT;
       i += gridDim.x * blockDim.x) {
    if (i < NX + NW + NO) {
      const float* src; ushort* dst; int j;
      if (i < NX)           { src = x;    dst = xb;    j = i; }
      else if (i < NX + NW) { src = wqkv; dst = wqkvb; j = i - NX; }
      else                  { src = wout; dst = woutb; j = i - NX - NW; }
      float4 v = ((const float4*)src)[j];
      ushort4 o;
      o.x = f2bf(v.x); o.y = f2bf(v.y); o.z = f2bf(v.z); o.w = f2bf(v.w);
      ((ushort4*)dst)[j] = o;
    } else {
      int j = i - NX - NW - NO;
      int fi = j & 31, s = j >> 5;
      float inv = expf(-(float)fi * (9.210340371976184f / 32.0f));
      float ang = (float)s * inv;
      float sn, cs;
      sincosf(ang, &sn, &cs);
      tab[j] = make_float2(cs, sn);
    }
  }
}

// ---------------- fused QKV GEMM v2: 8-wave blocks (2x4 quadrants, 64x32/wave) ----------------
// Same 128x128 tile, BK=64, 2-barrier loop, LDS-staged rope/transpose epilogue.
// 512 threads -> 24 waves/CU (6/SIMD) at 3 blocks/CU, double the prior TLP.
__global__ __launch_bounds__(512) void gemm_qkv(
    const ushort* __restrict__ A, const ushort* __restrict__ B,
    const float2* __restrict__ tab,
    ushort* __restrict__ Qh, ushort* __restrict__ Kh, ushort* __restrict__ Vt)
{
  union SM {
    struct { ushort As[128][64]; ushort Bs[128][64]; } s;  // 32 KB staging
    ushort vt[128][136];                                   // 34 KB epilogue alias
  };
  __shared__ __align__(16) SM sm;

  const int K = 1024;
  const int t = threadIdx.x;
  const int w = t >> 6, lane = t & 63;
  const int wm = w >> 2, wn = w & 3;        // 2 x 4 wave grid; wave owns 64x32
  const int lr = lane & 15, lk = lane >> 4;
  const int m0 = blockIdx.y * 128, n0 = blockIdx.x * 128;

  const int srow8 = lane >> 3;
  const int scol  = ((lane & 7) ^ srow8) * 8;

  f32x4 acc[4][2];
#pragma unroll
  for (int m = 0; m < 4; m++)
#pragma unroll
    for (int n = 0; n < 2; n++) acc[m][n] = (f32x4)(0.0f);

  for (int k0 = 0; k0 < K; k0 += 64) {
#pragma unroll
    for (int j = 0; j < 2; ++j) {
      const int c = w * 2 + j;               // chunk 0..15 (8 rows x 64 ushort)
      const int row = c * 8 + srow8;
      gload16(&A[(size_t)(m0 + row) * K + k0 + scol], &sm.s.As[c * 8][0]);
      gload16(&B[(size_t)(n0 + row) * K + k0 + scol], &sm.s.Bs[c * 8][0]);
    }
    __syncthreads();

    bf16x8 af[4][2], bfr[2][2];
#pragma unroll
    for (int m = 0; m < 4; m++)
#pragma unroll
      for (int kk = 0; kk < 2; kk++) {
        const int ch = (((kk << 2) + lk) ^ (lr & 7)) * 8;
        af[m][kk] = *(const bf16x8*)&sm.s.As[wm * 64 + m * 16 + lr][ch];
      }
#pragma unroll
    for (int n = 0; n < 2; n++)
#pragma unroll
      for (int kk = 0; kk < 2; kk++) {
        const int ch = (((kk << 2) + lk) ^ (lr & 7)) * 8;
        bfr[n][kk] = *(const bf16x8*)&sm.s.Bs[wn * 32 + n * 16 + lr][ch];
      }

    __builtin_amdgcn_s_setprio(1);
#pragma unroll
    for (int kk = 0; kk < 2; kk++)
#pragma unroll
      for (int m = 0; m < 4; m++)
#pragma unroll
        for (int n = 0; n < 2; n++)
          acc[m][n] = __builtin_amdgcn_mfma_f32_16x16x32_bf16(af[m][kk], bfr[n][kk], acc[m][n], 0, 0, 0);
    __builtin_amdgcn_s_setprio(0);

    __syncthreads();
  }

  const int reg  = n0 >> 10;       // 0=Q, 1=K, 2=V
  const int cb   = n0 & 1023;
  const int b    = m0 >> 11;
  const int s0   = m0 & 2047;
  const int h0   = cb >> 6;

  // stage raw bf16 tile in LDS
#pragma unroll
  for (int m = 0; m < 4; m++)
#pragma unroll
    for (int n = 0; n < 2; n++)
#pragma unroll
      for (int r = 0; r < 4; r++)
        sm.vt[wm * 64 + m * 16 + lk * 4 + r][wn * 32 + n * 16 + lr] = f2bf(acc[m][n][r]);
  __syncthreads();

  if (reg < 2) {
    // Q/K: vectorized rope read-out. 2048 chunks of 8 d-values, 512 threads x 4.
    ushort* dst = reg ? Kh : Qh;
    const float qs = reg ? 1.0f : 0.125f * 1.4426950408889634f;
#pragma unroll
    for (int p = 0; p < 4; ++p) {
      const int tid = t + p * 512;
      const int srow = tid >> 4;          // 0..127
      const int c8 = tid & 15;
      const int h = h0 + (c8 >> 3), d8 = (c8 & 7) * 8;
      const int s = s0 + srow;
      const ushort* lp = &sm.vt[srow][c8 * 8];
      float4 t0 = *(const float4*)&tab[s * 32 + (c8 & 7) * 4];
      float4 t1 = *(const float4*)&tab[s * 32 + (c8 & 7) * 4 + 2];
      uint32_t ow[4];
#pragma unroll
      for (int j = 0; j < 4; ++j) {
        float2 cs2 = (j < 2) ? ((const float2*)&t0)[j] : ((const float2*)&t1)[j - 2];
        float xr = bf2f(lp[2 * j]), xi = bf2f(lp[2 * j + 1]);
        float orr = (xr * cs2.x - xi * cs2.y) * qs;
        float oii = (xr * cs2.y + xi * cs2.x) * qs;
        ow[j] = (uint32_t)f2bf(orr) | ((uint32_t)f2bf(oii) << 16);
      }
      *(uint4*)&dst[((size_t)((b * NH + h) * S_LEN + s)) * 64 + d8] = *(const uint4*)ow;
    }
  } else {
    // V: transposed coalesced store to Vt (BH, 64, S)
#pragma unroll
    for (int p = 0; p < 4; ++p) {
      const int tid = t + p * 512;
      const int cl = tid >> 4;
      const int s8 = (tid & 15) * 8;
      const int h = h0 + (cl >> 6), d = cl & 63;
      ushort tmp[8];
#pragma unroll
      for (int j = 0; j < 8; j++) tmp[j] = sm.vt[s8 + j][cl];
      *(uint4*)&Vt[((size_t)((b * NH + h) * 64 + d)) * S_LEN + s0 + s8] = *(const uint4*)tmp;
    }
  }
}

// ---------------- out-proj GEMM v2: in-block K-split (unchanged) ----------------
__global__ __launch_bounds__(512) void gemm_out2(
    const ushort* __restrict__ A, const ushort* __restrict__ B, float* __restrict__ Cv)
{
  union SM {
    struct { ushort As[2][128][64]; ushort Bs[2][128][64]; } s;  // [kgroup] 64 KB
    float accs[128][128];                                        // merge alias 64 KB
  };
  __shared__ __align__(16) SM sm;

  const int N = 1024, K = 1024;
  const int t = threadIdx.x;
  const int w = t >> 6, lane = t & 63;
  const int kg = w >> 2;
  const int wq = w & 3;
  const int wm = wq >> 1, wn = wq & 1;
  const int lr = lane & 15, lk = lane >> 4;
  const int m0 = blockIdx.y * 128, n0 = blockIdx.x * 128;

  const int srow8 = lane >> 3;
  const int scol  = ((lane & 7) ^ srow8) * 8;

  f32x4 acc[4][4];
#pragma unroll
  for (int m = 0; m < 4; m++)
#pragma unroll
    for (int n = 0; n < 4; n++) acc[m][n] = (f32x4)(0.0f);

  for (int s = 0; s < 8; ++s) {
    const int k0 = kg * 512 + s * 64;
#pragma unroll
    for (int j = 0; j < 4; ++j) {
      const int c = wq * 4 + j;
      const int row = c * 8 + srow8;
      gload16(&A[(size_t)(m0 + row) * K + k0 + scol], &sm.s.As[kg][c * 8][0]);
      gload16(&B[(size_t)(n0 + row) * K + k0 + scol], &sm.s.Bs[kg][c * 8][0]);
    }
    __syncthreads();

    bf16x8 af[4][2], bfr[4][2];
#pragma unroll
    for (int m = 0; m < 4; m++)
#pragma unroll
      for (int kk = 0; kk < 2; kk++) {
        const int ch = (((kk << 2) + lk) ^ (lr & 7)) * 8;
        af[m][kk] = *(const bf16x8*)&sm.s.As[kg][wm * 64 + m * 16 + lr][ch];
      }
#pragma unroll
    for (int n = 0; n < 4; n++)
#pragma unroll
      for (int kk = 0; kk < 2; kk++) {
        const int ch = (((kk << 2) + lk) ^ (lr & 7)) * 8;
        bfr[n][kk] = *(const bf16x8*)&sm.s.Bs[kg][wn * 64 + n * 16 + lr][ch];
      }

    __builtin_amdgcn_s_setprio(1);
#pragma unroll
    for (int kk = 0; kk < 2; kk++)
#pragma unroll
      for (int m = 0; m < 4; m++)
#pragma unroll
        for (int n = 0; n < 4; n++)
          acc[m][n] = __builtin_amdgcn_mfma_f32_16x16x32_bf16(af[m][kk], bfr[n][kk], acc[m][n], 0, 0, 0);
    __builtin_amdgcn_s_setprio(0);

    __syncthreads();
  }

  if (kg == 1) {
#pragma unroll
    for (int m = 0; m < 4; m++)
#pragma unroll
      for (int n = 0; n < 4; n++)
#pragma unroll
        for (int r = 0; r < 4; r++)
          sm.accs[wm * 64 + m * 16 + lk * 4 + r][wn * 64 + n * 16 + lr] = acc[m][n][r];
  }
  __syncthreads();
  if (kg == 0) {
#pragma unroll
    for (int m = 0; m < 4; m++) {
      const int row = m0 + wm * 64 + m * 16 + lk * 4;
#pragma unroll
      for (int n = 0; n < 4; n++) {
        const int col = n0 + wn * 64 + n * 16 + lr;
#pragma unroll
        for (int r = 0; r < 4; r++) {
          float v = acc[m][n][r] + sm.accs[wm * 64 + m * 16 + lk * 4 + r][wn * 64 + n * 16 + lr];
          Cv[(size_t)(row + r) * N + col] = v;
        }
      }
    }
  }
}

// ---------------- causal flash attention v8: in-block split-KV merge (unchanged) ----------------
union SMemU8 {
  struct { ushort K[2][2][64][64]; ushort V[2][2][64][64]; } kv;  // [half][buf] 64 KB
  struct { ushort O[2][128][68]; float l[2][128]; } ep;
};

__global__ __launch_bounds__(512) void flash_attn8(
    const ushort* __restrict__ Qh, const ushort* __restrict__ Kh, const ushort* __restrict__ Vt,
    ushort* __restrict__ Ob)
{
  __shared__ __align__(16) SMemU8 sm;

  const int bh = blockIdx.x;
  const int y = blockIdx.y;
  const int qt = (y < 8) ? (15 - y) : (y - 8);
  const int b = bh >> 4, h = bh & 15;
  const int t = threadIdx.x;
  const int w = t >> 6, lane = t & 63;
  const int half = w >> 2, ws = w & 3;
  const int q5 = lane & 31, hi = lane >> 5;

  const int qbase_w = qt * 128 + ws * 32;
  const int qg = qbase_w + q5;

  bf16x8 qreg[4];
  {
    const size_t qb = ((size_t)bh * S_LEN + qg) * 64;
#pragma unroll
    for (int c = 0; c < 4; ++c)
      qreg[c] = *(const bf16x8*)&Qh[qb + c * 16 + hi * 8];
  }

  f32x16 oacc[2];
  oacc[0] = (f32x16)(0.0f); oacc[1] = (f32x16)(0.0f);
  float lsum = 0.0f;

  const ushort* Kg = &Kh[((size_t)bh * S_LEN) * 64];
  const ushort* Vg = &Vt[((size_t)bh * 64) * S_LEN];

  auto STAGE = [&](int bf, int jt) {
#pragma unroll
    for (int p = 0; p < 2; ++p) {
      const int row = ws * 16 + p * 8 + (lane >> 3);
      const int c16 = (lane & 7) ^ (row & 7);
      gload16(&Kg[((size_t)(jt * 64 + row)) * 64 + c16 * 8], &sm.kv.K[half][bf][ws * 16 + p * 8][0]);
      gload16(&Vg[((size_t)row) * S_LEN + jt * 64 + c16 * 8], &sm.kv.V[half][bf][ws * 16 + p * 8][0]);
    }
  };

  const int j0 = half ? (qt + 1) : 0;

  STAGE(0, j0);
  __syncthreads();

  int cur = 0;
  for (int i = 0; i <= qt; ++i) {
    if (i < qt) STAGE(cur ^ 1, j0 + i + 1);

    const int jt = j0 + i;
    const bool active = (jt * 64 <= qbase_w + 31);
    if (active) {
      f32x16 sc[2];
      sc[0] = (f32x16)(0.0f); sc[1] = (f32x16)(0.0f);
      __builtin_amdgcn_s_setprio(1);
#pragma unroll
      for (int kg = 0; kg < 2; ++kg) {
        const int kr = kg * 32 + q5;
#pragma unroll
        for (int c = 0; c < 4; ++c) {
          bf16x8 kf = *(const bf16x8*)&sm.kv.K[half][cur][kr][((c * 2 + hi) ^ (kr & 7)) * 8];
          sc[kg] = __builtin_amdgcn_mfma_f32_32x32x16_bf16(kf, qreg[c], sc[kg], 0, 0, 0);
        }
      }
      __builtin_amdgcn_s_setprio(0);

      if (jt * 64 + 63 > qbase_w) {
        const int kb = jt * 64;
#pragma unroll
        for (int r = 0; r < 16; ++r) {
          const int kl = kb + (r & 3) + 8 * (r >> 2) + 4 * hi;
          if (kl > qg)      sc[0][r] = -1e30f;
          if (kl + 32 > qg) sc[1][r] = -1e30f;
        }
      }

#pragma unroll
      for (int kg = 0; kg < 2; ++kg)
#pragma unroll
        for (int r = 0; r < 16; ++r)
          sc[kg][r] = __builtin_amdgcn_exp2f(sc[kg][r]);
      float rsum = tsum16(sc[0]) + tsum16(sc[1]);
      rsum += __shfl_xor(rsum, 32, 64);
      lsum += rsum;

      bf16x8 pf[4];
#pragma unroll
      for (int kc = 0; kc < 4; ++kc) {
        const int kg = kc >> 1, rA = (kc & 1) * 8, rB = rA + 4;
        uint32_t A0, A1, B0, B1;
        asm("v_cvt_pk_bf16_f32 %0, %1, %2" : "=v"(A0) : "v"(sc[kg][rA + 0]), "v"(sc[kg][rA + 1]));
        asm("v_cvt_pk_bf16_f32 %0, %1, %2" : "=v"(A1) : "v"(sc[kg][rA + 2]), "v"(sc[kg][rA + 3]));
        asm("v_cvt_pk_bf16_f32 %0, %1, %2" : "=v"(B0) : "v"(sc[kg][rB + 0]), "v"(sc[kg][rB + 1]));
        asm("v_cvt_pk_bf16_f32 %0, %1, %2" : "=v"(B1) : "v"(sc[kg][rB + 2]), "v"(sc[kg][rB + 3]));
        asm("v_permlane32_swap_b32 %0, %1" : "+v"(A0), "+v"(B0));
        asm("v_permlane32_swap_b32 %0, %1" : "+v"(A1), "+v"(B1));
        union { uint32_t u[4]; bf16x8 v; } cv;
        cv.u[0] = A0; cv.u[1] = A1; cv.u[2] = B0; cv.u[3] = B1;
        pf[kc] = cv.v;
      }

      __builtin_amdgcn_s_setprio(1);
#pragma unroll
      for (int dg = 0; dg < 2; ++dg) {
        const int vr = dg * 32 + q5;
#pragma unroll
        for (int kc = 0; kc < 4; ++kc) {
          bf16x8 vf = *(const bf16x8*)&sm.kv.V[half][cur][vr][((kc * 2 + hi) ^ (vr & 7)) * 8];
          oacc[dg] = __builtin_amdgcn_mfma_f32_32x32x16_bf16(vf, pf[kc], oacc[dg], 0, 0, 0);
        }
      }
      __builtin_amdgcn_s_setprio(0);
    }

    __syncthreads();
    cur ^= 1;
  }

  if (hi == 0)
    sm.ep.l[half][ws * 32 + q5] = lsum;
#pragma unroll
  for (int dg = 0; dg < 2; ++dg)
#pragma unroll
    for (int g = 0; g < 4; ++g) {
      ushort4 ok;
      ok.x = f2bf(oacc[dg][4 * g + 0]); ok.y = f2bf(oacc[dg][4 * g + 1]);
      ok.z = f2bf(oacc[dg][4 * g + 2]); ok.w = f2bf(oacc[dg][4 * g + 3]);
      *(ushort4*)&sm.ep.O[half][ws * 32 + q5][dg * 32 + g * 8 + 4 * hi] = ok;
    }
  __syncthreads();

  {
    const int row = t >> 2;
    const int dc = (t & 3) * 16;
    const float s = 1.0f / (sm.ep.l[0][row] + sm.ep.l[1][row]);
    const uint32_t* a = (const uint32_t*)&sm.ep.O[0][row][dc];
    const uint32_t* c = (const uint32_t*)&sm.ep.O[1][row][dc];
    uint32_t o[8];
#pragma unroll
    for (int j = 0; j < 8; ++j) {
      float lo = (bf2f_lo(a[j]) + bf2f_lo(c[j])) * s;
      float hv = (bf2f_hi(a[j]) + bf2f_hi(c[j])) * s;
      o[j] = (uint32_t)f2bf(lo) | ((uint32_t)f2bf(hv) << 16);
    }
    const size_t gb = ((size_t)(b * S_LEN + qt * 128 + row)) * DM + h * 64 + dc;
    *(uint4*)&Ob[gb]     = *(const uint4*)&o[0];
    *(uint4*)&Ob[gb + 8] = *(const uint4*)&o[4];
  }
}

extern "C" void kernel_launch(void* const* d_in, const int* in_sizes, int n_in,
                              void* d_out, int out_size, void* d_ws, size_t ws_size,
                              hipStream_t stream) {
  const float* x     = (const float*)d_in[0];
  const float* w_qkv = (const float*)d_in[2];
  const float* w_out = (const float*)d_in[3];
  float* out = (float*)d_out;

  char* ws = (char*)d_ws;
  ushort* xb    = (ushort*)(ws);
  ushort* wqkvb = (ushort*)(ws + 8388608);
  ushort* woutb = (ushort*)(ws + 14680064);
  ushort* Qh    = (ushort*)(ws + 41943040);
  ushort* Kh    = (ushort*)(ws + 50331648);
  ushort* Vt    = (ushort*)(ws + 58720256);
  ushort* Ob    = (ushort*)(ws + 67108864);
  float2* tab   = (float2*)(ws + 75497472);

  prep<<<2048, 256, 0, stream>>>(x, w_qkv, w_out, xb, wqkvb, woutb, tab);

  gemm_qkv<<<dim3(24, 32), 512, 0, stream>>>(xb, wqkvb, tab, Qh, Kh, Vt);

  flash_attn8<<<dim3(32, 16), 512, 0, stream>>>(Qh, Kh, Vt, Ob);

  gemm_out2<<<dim3(8, 32), 512, 0, stream>>>(Ob, woutb, out);
}

// Round 18
// 101.178 us; speedup vs baseline: 1.0801x; 1.0801x over previous
//
#include <hip/hip_runtime.h>
#include <hip/hip_bf16.h>
#include <cstdint>

typedef __attribute__((ext_vector_type(8))) __bf16 bf16x8;
typedef __attribute__((ext_vector_type(4))) float f32x4;
typedef __attribute__((ext_vector_type(16))) float f32x16;

#define DM 1024
#define NH 16
#define DH 64
#define S_LEN 2048
#define BATCH 2

__device__ __forceinline__ ushort f2bf(float f) {
  union { float f; uint32_t u; } v; v.f = f;
  uint32_t u = v.u;
  uint32_t r = (u + 0x7fffu + ((u >> 16) & 1u)) >> 16;
  return (ushort)r;
}
__device__ __forceinline__ float bf2f(ushort h) {
  union { uint32_t u; float f; } v; v.u = ((uint32_t)h) << 16;
  return v.f;
}
__device__ __forceinline__ float bf2f_lo(uint32_t u) {
  union { uint32_t u; float f; } v; v.u = u << 16;
  return v.f;
}
__device__ __forceinline__ float bf2f_hi(uint32_t u) {
  union { uint32_t u; float f; } v; v.u = u & 0xffff0000u;
  return v.f;
}

__device__ __forceinline__ void gload16(const void* g, void* l) {
  __builtin_amdgcn_global_load_lds(
      (const __attribute__((address_space(1))) unsigned*)g,
      (__attribute__((address_space(3))) unsigned*)l, 16, 0, 0);
}

__device__ __forceinline__ float tsum16(const f32x16& v) {
  float a = (v[0] + v[1]) + (v[2] + v[3]);
  float b = (v[4] + v[5]) + (v[6] + v[7]);
  float c = (v[8] + v[9]) + (v[10] + v[11]);
  float d = (v[12] + v[13]) + (v[14] + v[15]);
  return (a + b) + (c + d);
}

// ---------------- prep: all f32->bf16 casts + rope table in one kernel ----------------
__global__ void prep(const float* __restrict__ x, const float* __restrict__ wqkv,
                     const float* __restrict__ wout,
                     ushort* __restrict__ xb, ushort* __restrict__ wqkvb,
                     ushort* __restrict__ woutb, float2* __restrict__ tab) {
  const int NX = 1048576, NW = 786432, NO = 262144, NT = 65536;
  for (int i = blockIdx.x * blockDim.x + threadIdx.x; i < NX + NW + NO + NT;
       i += gridDim.x * blockDim.x) {
    if (i < NX + NW + NO) {
      const float* src; ushort* dst; int j;
      if (i < NX)           { src = x;    dst = xb;    j = i; }
      else if (i < NX + NW) { src = wqkv; dst = wqkvb; j = i - NX; }
      else                  { src = wout; dst = woutb; j = i - NX - NW; }
      float4 v = ((const float4*)src)[j];
      ushort4 o;
      o.x = f2bf(v.x); o.y = f2bf(v.y); o.z = f2bf(v.z); o.w = f2bf(v.w);
      ((ushort4*)dst)[j] = o;
    } else {
      int j = i - NX - NW - NO;
      int fi = j & 31, s = j >> 5;
      float inv = expf(-(float)fi * (9.210340371976184f / 32.0f));
      float ang = (float)s * inv;
      float sn, cs;
      sincosf(ang, &sn, &cs);
      tab[j] = make_float2(cs, sn);
    }
  }
}

// ---------------- fused QKV GEMM + LDS-staged rope/transpose epilogue (R16-verified) ----------------
__global__ __launch_bounds__(256) void gemm_qkv(
    const ushort* __restrict__ A, const ushort* __restrict__ B,
    const float2* __restrict__ tab,
    ushort* __restrict__ Qh, ushort* __restrict__ Kh, ushort* __restrict__ Vt)
{
  union SM {
    struct { ushort As[128][64]; ushort Bs[128][64]; } s;
    ushort vt[128][136];
  };
  __shared__ __align__(16) SM sm;

  const int K = 1024;
  const int t = threadIdx.x;
  const int w = t >> 6, lane = t & 63;
  const int wm = w >> 1, wn = w & 1;
  const int lr = lane & 15, lk = lane >> 4;
  const int m0 = blockIdx.y * 128, n0 = blockIdx.x * 128;

  const int srow8 = lane >> 3;
  const int scol  = ((lane & 7) ^ srow8) * 8;

  f32x4 acc[4][4];
#pragma unroll
  for (int m = 0; m < 4; m++)
#pragma unroll
    for (int n = 0; n < 4; n++) acc[m][n] = (f32x4)(0.0f);

  for (int k0 = 0; k0 < K; k0 += 64) {
#pragma unroll
    for (int j = 0; j < 4; ++j) {
      const int c = w * 4 + j;
      const int row = c * 8 + srow8;
      gload16(&A[(size_t)(m0 + row) * K + k0 + scol], &sm.s.As[c * 8][0]);
      gload16(&B[(size_t)(n0 + row) * K + k0 + scol], &sm.s.Bs[c * 8][0]);
    }
    __syncthreads();

    bf16x8 af[4][2], bfr[4][2];
#pragma unroll
    for (int m = 0; m < 4; m++)
#pragma unroll
      for (int kk = 0; kk < 2; kk++) {
        const int ch = (((kk << 2) + lk) ^ (lr & 7)) * 8;
        af[m][kk] = *(const bf16x8*)&sm.s.As[wm * 64 + m * 16 + lr][ch];
      }
#pragma unroll
    for (int n = 0; n < 4; n++)
#pragma unroll
      for (int kk = 0; kk < 2; kk++) {
        const int ch = (((kk << 2) + lk) ^ (lr & 7)) * 8;
        bfr[n][kk] = *(const bf16x8*)&sm.s.Bs[wn * 64 + n * 16 + lr][ch];
      }

    __builtin_amdgcn_s_setprio(1);
#pragma unroll
    for (int kk = 0; kk < 2; kk++)
#pragma unroll
      for (int m = 0; m < 4; m++)
#pragma unroll
        for (int n = 0; n < 4; n++)
          acc[m][n] = __builtin_amdgcn_mfma_f32_16x16x32_bf16(af[m][kk], bfr[n][kk], acc[m][n], 0, 0, 0);
    __builtin_amdgcn_s_setprio(0);

    __syncthreads();
  }

  const int reg  = n0 >> 10;
  const int cb   = n0 & 1023;
  const int b    = m0 >> 11;
  const int s0   = m0 & 2047;
  const int h0   = cb >> 6;

#pragma unroll
  for (int m = 0; m < 4; m++)
#pragma unroll
    for (int n = 0; n < 4; n++)
#pragma unroll
      for (int r = 0; r < 4; r++)
        sm.vt[wm * 64 + m * 16 + lk * 4 + r][wn * 64 + n * 16 + lr] = f2bf(acc[m][n][r]);
  __syncthreads();

  if (reg < 2) {
    ushort* dst = reg ? Kh : Qh;
    const float qs = reg ? 1.0f : 0.125f * 1.4426950408889634f;
#pragma unroll
    for (int p = 0; p < 8; ++p) {
      const int tid = t + p * 256;
      const int srow = tid >> 4;
      const int c8 = tid & 15;
      const int h = h0 + (c8 >> 3), d8 = (c8 & 7) * 8;
      const int s = s0 + srow;
      const ushort* lp = &sm.vt[srow][c8 * 8];
      float4 t0 = *(const float4*)&tab[s * 32 + (c8 & 7) * 4];
      float4 t1 = *(const float4*)&tab[s * 32 + (c8 & 7) * 4 + 2];
      uint32_t ow[4];
#pragma unroll
      for (int j = 0; j < 4; ++j) {
        float2 cs2 = (j < 2) ? ((const float2*)&t0)[j] : ((const float2*)&t1)[j - 2];
        float xr = bf2f(lp[2 * j]), xi = bf2f(lp[2 * j + 1]);
        float orr = (xr * cs2.x - xi * cs2.y) * qs;
        float oii = (xr * cs2.y + xi * cs2.x) * qs;
        ow[j] = (uint32_t)f2bf(orr) | ((uint32_t)f2bf(oii) << 16);
      }
      *(uint4*)&dst[((size_t)((b * NH + h) * S_LEN + s)) * 64 + d8] = *(const uint4*)ow;
    }
  } else {
#pragma unroll
    for (int p = 0; p < 8; ++p) {
      const int tid = t + p * 256;
      const int cl = tid >> 4;
      const int s8 = (tid & 15) * 8;
      const int h = h0 + (cl >> 6), d = cl & 63;
      ushort tmp[8];
#pragma unroll
      for (int j = 0; j < 8; j++) tmp[j] = sm.vt[s8 + j][cl];
      *(uint4*)&Vt[((size_t)((b * NH + h) * 64 + d)) * S_LEN + s0 + s8] = *(const uint4*)tmp;
    }
  }
}

// ---------------- out-proj GEMM v2: in-block K-split (R16-verified) ----------------
__global__ __launch_bounds__(512) void gemm_out2(
    const ushort* __restrict__ A, const ushort* __restrict__ B, float* __restrict__ Cv)
{
  union SM {
    struct { ushort As[2][128][64]; ushort Bs[2][128][64]; } s;
    float accs[128][128];
  };
  __shared__ __align__(16) SM sm;

  const int N = 1024, K = 1024;
  const int t = threadIdx.x;
  const int w = t >> 6, lane = t & 63;
  const int kg = w >> 2;
  const int wq = w & 3;
  const int wm = wq >> 1, wn = wq & 1;
  const int lr = lane & 15, lk = lane >> 4;
  const int m0 = blockIdx.y * 128, n0 = blockIdx.x * 128;

  const int srow8 = lane >> 3;
  const int scol  = ((lane & 7) ^ srow8) * 8;

  f32x4 acc[4][4];
#pragma unroll
  for (int m = 0; m < 4; m++)
#pragma unroll
    for (int n = 0; n < 4; n++) acc[m][n] = (f32x4)(0.0f);

  for (int s = 0; s < 8; ++s) {
    const int k0 = kg * 512 + s * 64;
#pragma unroll
    for (int j = 0; j < 4; ++j) {
      const int c = wq * 4 + j;
      const int row = c * 8 + srow8;
      gload16(&A[(size_t)(m0 + row) * K + k0 + scol], &sm.s.As[kg][c * 8][0]);
      gload16(&B[(size_t)(n0 + row) * K + k0 + scol], &sm.s.Bs[kg][c * 8][0]);
    }
    __syncthreads();

    bf16x8 af[4][2], bfr[4][2];
#pragma unroll
    for (int m = 0; m < 4; m++)
#pragma unroll
      for (int kk = 0; kk < 2; kk++) {
        const int ch = (((kk << 2) + lk) ^ (lr & 7)) * 8;
        af[m][kk] = *(const bf16x8*)&sm.s.As[kg][wm * 64 + m * 16 + lr][ch];
      }
#pragma unroll
    for (int n = 0; n < 4; n++)
#pragma unroll
      for (int kk = 0; kk < 2; kk++) {
        const int ch = (((kk << 2) + lk) ^ (lr & 7)) * 8;
        bfr[n][kk] = *(const bf16x8*)&sm.s.Bs[kg][wn * 64 + n * 16 + lr][ch];
      }

    __builtin_amdgcn_s_setprio(1);
#pragma unroll
    for (int kk = 0; kk < 2; kk++)
#pragma unroll
      for (int m = 0; m < 4; m++)
#pragma unroll
        for (int n = 0; n < 4; n++)
          acc[m][n] = __builtin_amdgcn_mfma_f32_16x16x32_bf16(af[m][kk], bfr[n][kk], acc[m][n], 0, 0, 0);
    __builtin_amdgcn_s_setprio(0);

    __syncthreads();
  }

  if (kg == 1) {
#pragma unroll
    for (int m = 0; m < 4; m++)
#pragma unroll
      for (int n = 0; n < 4; n++)
#pragma unroll
        for (int r = 0; r < 4; r++)
          sm.accs[wm * 64 + m * 16 + lk * 4 + r][wn * 64 + n * 16 + lr] = acc[m][n][r];
  }
  __syncthreads();
  if (kg == 0) {
#pragma unroll
    for (int m = 0; m < 4; m++) {
      const int row = m0 + wm * 64 + m * 16 + lk * 4;
#pragma unroll
      for (int n = 0; n < 4; n++) {
        const int col = n0 + wn * 64 + n * 16 + lr;
#pragma unroll
        for (int r = 0; r < 4; r++) {
          float v = acc[m][n][r] + sm.accs[wm * 64 + m * 16 + lk * 4 + r][wn * 64 + n * 16 + lr];
          Cv[(size_t)(row + r) * N + col] = v;
        }
      }
    }
  }
}

// ---------------- causal flash attention v8: in-block split-KV merge (R16-verified) ----------------
union SMemU8 {
  struct { ushort K[2][2][64][64]; ushort V[2][2][64][64]; } kv;  // [half][buf] 64 KB
  struct { ushort O[2][128][68]; float l[2][128]; } ep;
};

__global__ __launch_bounds__(512) void flash_attn8(
    const ushort* __restrict__ Qh, const ushort* __restrict__ Kh, const ushort* __restrict__ Vt,
    ushort* __restrict__ Ob)
{
  __shared__ __align__(16) SMemU8 sm;

  const int bh = blockIdx.x;
  const int y = blockIdx.y;
  const int qt = (y < 8) ? (15 - y) : (y - 8);
  const int b = bh >> 4, h = bh & 15;
  const int t = threadIdx.x;
  const int w = t >> 6, lane = t & 63;
  const int half = w >> 2, ws = w & 3;
  const int q5 = lane & 31, hi = lane >> 5;

  const int qbase_w = qt * 128 + ws * 32;
  const int qg = qbase_w + q5;

  bf16x8 qreg[4];
  {
    const size_t qb = ((size_t)bh * S_LEN + qg) * 64;
#pragma unroll
    for (int c = 0; c < 4; ++c)
      qreg[c] = *(const bf16x8*)&Qh[qb + c * 16 + hi * 8];
  }

  f32x16 oacc[2];
  oacc[0] = (f32x16)(0.0f); oacc[1] = (f32x16)(0.0f);
  float lsum = 0.0f;

  const ushort* Kg = &Kh[((size_t)bh * S_LEN) * 64];
  const ushort* Vg = &Vt[((size_t)bh * 64) * S_LEN];

  auto STAGE = [&](int bf, int jt) {
#pragma unroll
    for (int p = 0; p < 2; ++p) {
      const int row = ws * 16 + p * 8 + (lane >> 3);
      const int c16 = (lane & 7) ^ (row & 7);
      gload16(&Kg[((size_t)(jt * 64 + row)) * 64 + c16 * 8], &sm.kv.K[half][bf][ws * 16 + p * 8][0]);
      gload16(&Vg[((size_t)row) * S_LEN + jt * 64 + c16 * 8], &sm.kv.V[half][bf][ws * 16 + p * 8][0]);
    }
  };

  const int j0 = half ? (qt + 1) : 0;

  STAGE(0, j0);
  __syncthreads();

  int cur = 0;
  for (int i = 0; i <= qt; ++i) {
    if (i < qt) STAGE(cur ^ 1, j0 + i + 1);

    const int jt = j0 + i;
    const bool active = (jt * 64 <= qbase_w + 31);
    if (active) {
      f32x16 sc[2];
      sc[0] = (f32x16)(0.0f); sc[1] = (f32x16)(0.0f);
      __builtin_amdgcn_s_setprio(1);
#pragma unroll
      for (int kg = 0; kg < 2; ++kg) {
        const int kr = kg * 32 + q5;
#pragma unroll
        for (int c = 0; c < 4; ++c) {
          bf16x8 kf = *(const bf16x8*)&sm.kv.K[half][cur][kr][((c * 2 + hi) ^ (kr & 7)) * 8];
          sc[kg] = __builtin_amdgcn_mfma_f32_32x32x16_bf16(kf, qreg[c], sc[kg], 0, 0, 0);
        }
      }
      __builtin_amdgcn_s_setprio(0);

      if (jt * 64 + 63 > qbase_w) {
        const int kb = jt * 64;
#pragma unroll
        for (int r = 0; r < 16; ++r) {
          const int kl = kb + (r & 3) + 8 * (r >> 2) + 4 * hi;
          if (kl > qg)      sc[0][r] = -1e30f;
          if (kl + 32 > qg) sc[1][r] = -1e30f;
        }
      }

#pragma unroll
      for (int kg = 0; kg < 2; ++kg)
#pragma unroll
        for (int r = 0; r < 16; ++r)
          sc[kg][r] = __builtin_amdgcn_exp2f(sc[kg][r]);
      float rsum = tsum16(sc[0]) + tsum16(sc[1]);
      rsum += __shfl_xor(rsum, 32, 64);
      lsum += rsum;

      bf16x8 pf[4];
#pragma unroll
      for (int kc = 0; kc < 4; ++kc) {
        const int kg = kc >> 1, rA = (kc & 1) * 8, rB = rA + 4;
        uint32_t A0, A1, B0, B1;
        asm("v_cvt_pk_bf16_f32 %0, %1, %2" : "=v"(A0) : "v"(sc[kg][rA + 0]), "v"(sc[kg][rA + 1]));
        asm("v_cvt_pk_bf16_f32 %0, %1, %2" : "=v"(A1) : "v"(sc[kg][rA + 2]), "v"(sc[kg][rA + 3]));
        asm("v_cvt_pk_bf16_f32 %0, %1, %2" : "=v"(B0) : "v"(sc[kg][rB + 0]), "v"(sc[kg][rB + 1]));
        asm("v_cvt_pk_bf16_f32 %0, %1, %2" : "=v"(B1) : "v"(sc[kg][rB + 2]), "v"(sc[kg][rB + 3]));
        asm("v_permlane32_swap_b32 %0, %1" : "+v"(A0), "+v"(B0));
        asm("v_permlane32_swap_b32 %0, %1" : "+v"(A1), "+v"(B1));
        union { uint32_t u[4]; bf16x8 v; } cv;
        cv.u[0] = A0; cv.u[1] = A1; cv.u[2] = B0; cv.u[3] = B1;
        pf[kc] = cv.v;
      }

      __builtin_amdgcn_s_setprio(1);
#pragma unroll
      for (int dg = 0; dg < 2; ++dg) {
        const int vr = dg * 32 + q5;
#pragma unroll
        for (int kc = 0; kc < 4; ++kc) {
          bf16x8 vf = *(const bf16x8*)&sm.kv.V[half][cur][vr][((kc * 2 + hi) ^ (vr & 7)) * 8];
          oacc[dg] = __builtin_amdgcn_mfma_f32_32x32x16_bf16(vf, pf[kc], oacc[dg], 0, 0, 0);
        }
      }
      __builtin_amdgcn_s_setprio(0);
    }

    __syncthreads();
    cur ^= 1;
  }

  if (hi == 0)
    sm.ep.l[half][ws * 32 + q5] = lsum;
#pragma unroll
  for (int dg = 0; dg < 2; ++dg)
#pragma unroll
    for (int g = 0; g < 4; ++g) {
      ushort4 ok;
      ok.x = f2bf(oacc[dg][4 * g + 0]); ok.y = f2bf(oacc[dg][4 * g + 1]);
      ok.z = f2bf(oacc[dg][4 * g + 2]); ok.w = f2bf(oacc[dg][4 * g + 3]);
      *(ushort4*)&sm.ep.O[half][ws * 32 + q5][dg * 32 + g * 8 + 4 * hi] = ok;
    }
  __syncthreads();

  {
    const int row = t >> 2;
    const int dc = (t & 3) * 16;
    const float s = 1.0f / (sm.ep.l[0][row] + sm.ep.l[1][row]);
    const uint32_t* a = (const uint32_t*)&sm.ep.O[0][row][dc];
    const uint32_t* c = (const uint32_t*)&sm.ep.O[1][row][dc];
    uint32_t o[8];
#pragma unroll
    for (int j = 0; j < 8; ++j) {
      float lo = (bf2f_lo(a[j]) + bf2f_lo(c[j])) * s;
      float hv = (bf2f_hi(a[j]) + bf2f_hi(c[j])) * s;
      o[j] = (uint32_t)f2bf(lo) | ((uint32_t)f2bf(hv) << 16);
    }
    const size_t gb = ((size_t)(b * S_LEN + qt * 128 + row)) * DM + h * 64 + dc;
    *(uint4*)&Ob[gb]     = *(const uint4*)&o[0];
    *(uint4*)&Ob[gb + 8] = *(const uint4*)&o[4];
  }
}

extern "C" void kernel_launch(void* const* d_in, const int* in_sizes, int n_in,
                              void* d_out, int out_size, void* d_ws, size_t ws_size,
                              hipStream_t stream) {
  const float* x     = (const float*)d_in[0];
  const float* w_qkv = (const float*)d_in[2];
  const float* w_out = (const float*)d_in[3];
  float* out = (float*)d_out;

  char* ws = (char*)d_ws;
  ushort* xb    = (ushort*)(ws);
  ushort* wqkvb = (ushort*)(ws + 8388608);
  ushort* woutb = (ushort*)(ws + 14680064);
  ushort* Qh    = (ushort*)(ws + 41943040);
  ushort* Kh    = (ushort*)(ws + 50331648);
  ushort* Vt    = (ushort*)(ws + 58720256);
  ushort* Ob    = (ushort*)(ws + 67108864);
  float2* tab   = (float2*)(ws + 75497472);

  prep<<<2048, 256, 0, stream>>>(x, w_qkv, w_out, xb, wqkvb, woutb, tab);

  gemm_qkv<<<dim3(24, 32), 256, 0, stream>>>(xb, wqkvb, tab, Qh, Kh, Vt);

  flash_attn8<<<dim3(32, 16), 512, 0, stream>>>(Qh, Kh, Vt, Ob);

  gemm_out2<<<dim3(8, 32), 512, 0, stream>>>(Ob, woutb, out);
}